// Round 11
// baseline (482.634 us; speedup 1.0000x reference)
//
#include <hip/hip_runtime.h>
#include <hip/hip_bf16.h>

#define DIV_UP(a,b) (((a)+(b)-1)/(b))

static const int NN  = 50000;   // nodes
static const int NE  = 400000;  // edges
static const int DIN = 512;
static const int DH  = 256;
static const int NG  = 64;      // graphs
static const int MAXDEG = 64;   // Poisson(8) max over 50K nodes ~30; clamped

typedef unsigned short u16;
typedef unsigned int   u32;
typedef __attribute__((ext_vector_type(8))) short bf16x8;   // 8 bf16 (4 VGPRs)
typedef __attribute__((ext_vector_type(4))) float f32x4;

#define AS1(p) ((const __attribute__((address_space(1))) void*)(p))
#define AS3(p) ((__attribute__((address_space(3))) void*)(p))

__device__ inline u16 f2bf(float f) {
  u32 u = __float_as_uint(f);
  u += 0x7fffu + ((u >> 16) & 1u);   // round-to-nearest-even
  return (u16)(u >> 16);
}
__device__ inline float bf2f(u16 h) { return __uint_as_float(((u32)h) << 16); }
__device__ inline void unpack2(u32 u, float& lo, float& hi) {
  lo = __uint_as_float(u << 16);
  hi = __uint_as_float(u & 0xffff0000u);
}
__device__ inline u32 pack2(float lo, float hi) {
  return (u32)f2bf(lo) | ((u32)f2bf(hi) << 16);
}

// ================= fused setup: X cvt | 6 weight transposes | BN fold | zero
struct SetupArgs {
  const float* x; u16* Xb;
  const float* Wsrc[6]; u16* Wdst[6];      // [0]=W1L0 512x256, [1..2]=W1L1/2, [3..5]=W2L0..2
  const float* bn[15];                     // [l*5]: b1,gamma,beta,mean,var
  float* scsh;
  int* cnt; float* PL;
};
static const int NB_X = (NN * DIN / 8) / 256;                 // 12500
static const int NB_W = (131072 + 5 * 65536) / 256;           // 1792
static const int NB_Z = DIV_UP(NN + NG * 768, 256);           // 388

__global__ __launch_bounds__(256) void k_setup(SetupArgs a) {
  int b = blockIdx.x;
  if (b < NB_X) {
    int i = b * 256 + threadIdx.x;
    const float4* p = (const float4*)a.x + (size_t)i * 2;
    float4 f0 = p[0], f1 = p[1];
    uint4 o;
    o.x = pack2(f0.x, f0.y); o.y = pack2(f0.z, f0.w);
    o.z = pack2(f1.x, f1.y); o.w = pack2(f1.z, f1.w);
    ((uint4*)a.Xb)[i] = o;
  } else if (b < NB_X + NB_W) {
    int idx = (b - NB_X) * 256 + threadIdx.x;
    if (idx < 131072) {                       // W1[0]: K=512, N=256
      int n = idx >> 9, k = idx & 511;
      a.Wdst[0][idx] = f2bf(a.Wsrc[0][(size_t)k * 256 + n]);
    } else {
      int r = idx - 131072;
      int s = 1 + (r >> 16);
      int ri = r & 65535;
      int n = ri >> 8, k = ri & 255;
      a.Wdst[s][ri] = f2bf(a.Wsrc[s][(size_t)k * 256 + n]);
    }
  } else if (b < NB_X + NB_W + 3) {
    int l = b - NB_X - NB_W, ch = threadIdx.x;
    float sc = rsqrtf(a.bn[l * 5 + 4][ch] + 1e-5f) * a.bn[l * 5 + 1][ch];
    float sh = (a.bn[l * 5 + 0][ch] - a.bn[l * 5 + 3][ch]) * sc + a.bn[l * 5 + 2][ch];
    a.scsh[l * 512 + ch] = sc;
    a.scsh[l * 512 + 256 + ch] = sh;
  } else {
    int i = (b - NB_X - NB_W - 3) * 256 + threadIdx.x;
    if (i < NN) a.cnt[i] = 0;
    else if (i - NN < NG * 768) a.PL[i - NN] = 0.f;
  }
}

// ================= padded adjacency build ========
__global__ __launch_bounds__(256) void k_fill2(const int* __restrict__ src,
                                               const int* __restrict__ dst,
                                               int* __restrict__ cnt,
                                               int* __restrict__ adj, int nE) {
  int e = blockIdx.x * 256 + threadIdx.x;
  if (e >= nE) return;
  int d = dst[e];
  int pos = atomicAdd(&cnt[d], 1);
  if (pos < MAXDEG) adj[(size_t)d * MAXDEG + pos] = src[e];
}

// ============ gather core: a0..a7 = Y[gr] + sum_nbr Y[j] at channel c ======
__device__ inline void gather_row(const u16* __restrict__ Y, const int* __restrict__ cnt,
                                  const int* __restrict__ adj, int gr, int c,
                                  float& a0, float& a1, float& a2, float& a3,
                                  float& a4, float& a5, float& a6, float& a7) {
  uint4 v = *(const uint4*)(Y + (size_t)gr * DH + c);
  unpack2(v.x,a0,a1); unpack2(v.y,a2,a3); unpack2(v.z,a4,a5); unpack2(v.w,a6,a7);
  int deg = cnt[gr]; if (deg > MAXDEG) deg = MAXDEG;
  const int* row = adj + (size_t)gr * MAXDEG;
  int e = 0;
  for (; e + 8 <= deg; e += 8) {
    uint4 w[8];
#pragma unroll
    for (int u = 0; u < 8; ++u)
      w[u] = *(const uint4*)(Y + (size_t)row[e + u] * DH + c);
#pragma unroll
    for (int u = 0; u < 8; ++u) {
      float b0,b1,b2,b3,b4,b5,b6,b7;
      unpack2(w[u].x,b0,b1); unpack2(w[u].y,b2,b3);
      unpack2(w[u].z,b4,b5); unpack2(w[u].w,b6,b7);
      a0+=b0; a1+=b1; a2+=b2; a3+=b3; a4+=b4; a5+=b5; a6+=b6; a7+=b7;
    }
  }
  for (; e + 4 <= deg; e += 4) {
    uint4 w[4];
#pragma unroll
    for (int u = 0; u < 4; ++u)
      w[u] = *(const uint4*)(Y + (size_t)row[e + u] * DH + c);
#pragma unroll
    for (int u = 0; u < 4; ++u) {
      float b0,b1,b2,b3,b4,b5,b6,b7;
      unpack2(w[u].x,b0,b1); unpack2(w[u].y,b2,b3);
      unpack2(w[u].z,b4,b5); unpack2(w[u].w,b6,b7);
      a0+=b0; a1+=b1; a2+=b2; a3+=b3; a4+=b4; a5+=b5; a6+=b6; a7+=b7;
    }
  }
  for (; e < deg; ++e) {
    uint4 w = *(const uint4*)(Y + (size_t)row[e] * DH + c);
    float b0,b1,b2,b3,b4,b5,b6,b7;
    unpack2(w.x,b0,b1); unpack2(w.y,b2,b3); unpack2(w.z,b4,b5); unpack2(w.w,b6,b7);
    a0+=b0; a1+=b1; a2+=b2; a3+=b3; a4+=b4; a5+=b5; a6+=b6; a7+=b7;
  }
}

// ================= GEMM1: Y = A @ WT  (full-N 128x256 tile, BK=32, dbuf) ====
// Pre-swizzled global source for As/Bs (T21) -> 2-way LDS reads.
template <int K>
__global__ __launch_bounds__(512, 4) void k_gemm1(
    const u16* __restrict__ A, const u16* __restrict__ BT,
    u16* __restrict__ out, int M) {
  const int N = 256;
  __shared__ __align__(16) u16 sm[32768];   // staging 2x12288 head; Cs 32768 reuse
  u16* Cs = sm;
  const int bm = blockIdx.x * 128;
  const int tid = threadIdx.x;
  const int lane = tid & 63;
  const int wave = tid >> 6;        // 0..7
  const int wm = (wave >> 2) * 64;  // 0,64
  const int wn = (wave & 3) * 64;   // 0,64,128,192
  const int l15 = lane & 15;
  const int l4 = lane >> 4;
  const int sw = (lane >> 1) & 3;   // read-slot XOR
  const int srow = lane >> 2;
  const int sslot = (lane & 3) ^ ((lane >> 3) & 3);  // pre-swizzled source slot

  auto STAGE = [&](int buf, int k0) {
    u16* As = sm + buf * 12288;
    u16* Bs = As + 4096;
    {
      int row = wave * 16 + srow;
      int grA = bm + row; if (grA >= M) grA = M - 1;
      __builtin_amdgcn_global_load_lds(AS1(A + (size_t)grA * K + k0 + sslot * 8),
                                       AS3(As + wave * 512), 16, 0, 0);
    }
#pragma unroll
    for (int i = 0; i < 2; ++i) {
      int q = wave * 2 + i;
      int row = q * 16 + srow;
      __builtin_amdgcn_global_load_lds(AS1(BT + (size_t)row * K + k0 + sslot * 8),
                                       AS3(Bs + q * 512), 16, 0, 0);
    }
  };

  f32x4 acc[4][4] = {};
  const int nt = K >> 5;
  STAGE(0, 0);
  int cur = 0;
  for (int t = 0; t < nt; ++t) {
    __syncthreads();
    if (t + 1 < nt) STAGE(cur ^ 1, (t + 1) << 5);
    u16* As = sm + cur * 12288;
    u16* Bs = As + 4096;
    bf16x8 af[4], bf_[4];
#pragma unroll
    for (int f = 0; f < 4; ++f) {
      af[f]  = *(const bf16x8*)(As + (wm + f * 16 + l15) * 32 + ((l4 ^ sw) << 3));
      bf_[f] = *(const bf16x8*)(Bs + (wn + f * 16 + l15) * 32 + ((l4 ^ sw) << 3));
    }
#pragma unroll
    for (int i = 0; i < 4; ++i)
#pragma unroll
      for (int j = 0; j < 4; ++j)
        acc[i][j] = __builtin_amdgcn_mfma_f32_16x16x32_bf16(af[i], bf_[j], acc[i][j], 0, 0, 0);
    cur ^= 1;
  }

  __syncthreads();
#pragma unroll
  for (int j = 0; j < 4; ++j) {
    int n = wn + j * 16 + l15;
#pragma unroll
    for (int i = 0; i < 4; ++i) {
#pragma unroll
      for (int r = 0; r < 4; ++r) {
        int row = wm + i * 16 + l4 * 4 + r;
        Cs[row * 256 + n] = f2bf(acc[i][j][r]);
      }
    }
  }
  __syncthreads();
  const int ccol = (tid & 31) * 8;
#pragma unroll
  for (int p = 0; p < 8; ++p) {
    int row = p * 16 + (tid >> 5);
    int gm = bm + row;
    if (gm < M)
      *(uint4*)(out + (size_t)gm * N + ccol) = *(const uint4*)(Cs + row * 256 + ccol);
  }
}

// ====== fused GIN tail: gather+BN+relu -> LDS A-tile; h = relu(A@W2+b2);
//        fused per-graph pool; optional global h store. 64-row tile, K=N=256.
// B fragments read directly from global (W2T is L2-resident) -> LDS = At only
// (32.3 KB) -> 4 blocks/CU, 32 waves/CU during the latency-bound gather.
template <int STORE>
__global__ __launch_bounds__(512, 8) void k_gin2(
    const u16* __restrict__ Y, const int* __restrict__ cnt,
    const int* __restrict__ adj, const float* __restrict__ scsh,
    const u16* __restrict__ BT, const float* __restrict__ bias,
    u16* __restrict__ out, const int* __restrict__ batch,
    float* __restrict__ PL, int poolOff, int M) {
  __shared__ __align__(16) u16 At[64 * 256];     // 32 KB; swizzled; Cs reuse
  __shared__ int bsh[64];
  const int bm = blockIdx.x * 64;
  const int tid = threadIdx.x;
  const int lane = tid & 63;
  const int wave = tid >> 6;          // 0..7
  const int wm = (wave >> 2) * 32;    // 0,32
  const int wn = (wave & 3) * 64;     // 0,64,128,192
  const int l15 = lane & 15;
  const int l4 = lane >> 4;
  const int a7 = lane & 7;            // At read-row XOR

  if (tid < 64) bsh[tid] = (bm + tid < M) ? batch[bm + tid] : -1;

  // ---- gather 64 rows into swizzled At ----
  {
    const int c = (tid & 31) << 3;
    float4 sc0 = *(const float4*)(scsh + c);
    float4 sc1 = *(const float4*)(scsh + c + 4);
    float4 sh0 = *(const float4*)(scsh + 256 + c);
    float4 sh1 = *(const float4*)(scsh + 256 + c + 4);
    const int slot0 = c >> 3;           // logical 16B slot (0..31)
#pragma unroll 1
    for (int p = 0; p < 4; ++p) {
      int rl = p * 16 + (tid >> 5);     // local row 0..63
      int gr = bm + rl; if (gr >= M) gr = M - 1;
      float a0,a1,a2,a3,a4,a5,a6,a7v;
      gather_row(Y, cnt, adj, gr, c, a0,a1,a2,a3,a4,a5,a6,a7v);
      a0 = fmaxf(fmaf(a0, sc0.x, sh0.x), 0.f);
      a1 = fmaxf(fmaf(a1, sc0.y, sh0.y), 0.f);
      a2 = fmaxf(fmaf(a2, sc0.z, sh0.z), 0.f);
      a3 = fmaxf(fmaf(a3, sc0.w, sh0.w), 0.f);
      a4 = fmaxf(fmaf(a4, sc1.x, sh1.x), 0.f);
      a5 = fmaxf(fmaf(a5, sc1.y, sh1.y), 0.f);
      a6 = fmaxf(fmaf(a6, sc1.z, sh1.z), 0.f);
      a7v = fmaxf(fmaf(a7v, sc1.w, sh1.w), 0.f);
      uint4 o;
      o.x = pack2(a0,a1); o.y = pack2(a2,a3); o.z = pack2(a4,a5); o.w = pack2(a6,a7v);
      *(uint4*)(At + rl * 256 + ((slot0 ^ (rl & 7)) << 3)) = o;
    }
  }
  __syncthreads();                     // At ready; read-only through K-loop

  f32x4 acc[2][4] = {};
#pragma unroll 2
  for (int t = 0; t < 8; ++t) {
    bf16x8 af[2], bf_[4];
#pragma unroll
    for (int j = 0; j < 4; ++j) {
      int row = wn + j * 16 + l15;
      bf_[j] = *(const bf16x8*)(BT + (size_t)row * 256 + (t << 5) + l4 * 8);
    }
#pragma unroll
    for (int f = 0; f < 2; ++f) {
      int row = wm + f * 16 + l15;
      af[f] = *(const bf16x8*)(At + row * 256 + ((((t << 2) + l4) ^ a7) << 3));
    }
#pragma unroll
    for (int i = 0; i < 2; ++i)
#pragma unroll
      for (int j = 0; j < 4; ++j)
        acc[i][j] = __builtin_amdgcn_mfma_f32_16x16x32_bf16(af[i], bf_[j], acc[i][j], 0, 0, 0);
  }

  __syncthreads();            // At reads done; reuse as Cs
  u16* Cs = At;
#pragma unroll
  for (int j = 0; j < 4; ++j) {
    int n = wn + j * 16 + l15;
    float sh = bias[n];
#pragma unroll
    for (int i = 0; i < 2; ++i) {
#pragma unroll
      for (int r = 0; r < 4; ++r) {
        int row = wm + i * 16 + l4 * 4 + r;
        Cs[row * 256 + n] = f2bf(fmaxf(acc[i][j][r] + sh, 0.f));
      }
    }
  }
  __syncthreads();

  if (STORE) {
    const int ccol = (tid & 31) * 8;
#pragma unroll
    for (int p = 0; p < 4; ++p) {
      int row = p * 16 + (tid >> 5);
      int gm = bm + row;
      if (gm < M)
        *(uint4*)(out + (size_t)gm * DH + ccol) = *(const uint4*)(Cs + row * 256 + ccol);
    }
  }

  {  // pool: 2 halves x 32 rows, 256 cols
    int col = tid & 255;
    int half = tid >> 8;
    float accv = 0.f;
    int cg = bsh[half * 32];
    for (int r = 0; r < 32; ++r) {
      int row = half * 32 + r;
      int g = bsh[row];
      if (g != cg) {
        if (cg >= 0) unsafeAtomicAdd(&PL[cg * 768 + poolOff + col], accv);
        accv = 0.f;
        cg = g;
      }
      accv += bf2f(Cs[row * 256 + col]);
    }
    if (cg >= 0) unsafeAtomicAdd(&PL[cg * 768 + poolOff + col], accv);
  }
}

// ================= head =================
__global__ __launch_bounds__(64) void k_head1(const float* __restrict__ P,
                                              const float* __restrict__ W,
                                              const float* __restrict__ b,
                                              float* __restrict__ Q) {
  __shared__ float pr[768];
  int g = blockIdx.x, t = threadIdx.x;
  for (int i = t; i < 768; i += 64) pr[i] = P[g * 768 + i];
  __syncthreads();
  float acc = b[t];
  for (int k = 0; k < 768; ++k) acc = fmaf(pr[k], W[k * 64 + t], acc);
  Q[g * 64 + t] = fmaxf(acc, 0.f);
}

__global__ __launch_bounds__(64) void k_head2(const float* __restrict__ Q,
                                              const float* __restrict__ W,
                                              const float* __restrict__ b,
                                              float* __restrict__ out) {
  int g = threadIdx.x;
  if (g >= 64) return;
  float h0 = b[0], h1 = b[1];
  for (int k = 0; k < 64; ++k) {
    float q = Q[g * 64 + k];
    h0 = fmaf(q, W[k * 2 + 0], h0);
    h1 = fmaf(q, W[k * 2 + 1], h1);
  }
  out[g * 2 + 0] = h0;
  out[g * 2 + 1] = h1;
  float m = fmaxf(h0, h1);
  float lse = m + logf(expf(h0 - m) + expf(h1 - m));
  out[128 + g * 2 + 0] = h0 - lse;
  out[128 + g * 2 + 1] = h1 - lse;
}

extern "C" void kernel_launch(void* const* d_in, const int* in_sizes, int n_in,
                              void* d_out, int out_size, void* d_ws,
                              size_t ws_size, hipStream_t stream) {
  const float* x = (const float*)d_in[0];
  const int* ei = (const int*)d_in[1];
  const int* batch = (const int*)d_in[2];
  const float* W1[3]; const float* b1[3]; const float* ga[3]; const float* be[3];
  const float* mu[3]; const float* va[3]; const float* W2[3]; const float* b2[3];
  for (int l = 0; l < 3; ++l) {
    int base = 3 + 8 * l;
    W1[l] = (const float*)d_in[base + 0];
    b1[l] = (const float*)d_in[base + 1];
    ga[l] = (const float*)d_in[base + 2];
    be[l] = (const float*)d_in[base + 3];
    mu[l] = (const float*)d_in[base + 4];
    va[l] = (const float*)d_in[base + 5];
    W2[l] = (const float*)d_in[base + 6];
    b2[l] = (const float*)d_in[base + 7];
  }
  const float* l1W = (const float*)d_in[27];
  const float* l1b = (const float*)d_in[28];
  const float* l2W = (const float*)d_in[29];
  const float* l2b = (const float*)d_in[30];
  const int* src = ei;
  const int* dst = ei + NE;
  float* out = (float*)d_out;

  // ---- workspace layout ----
  char* w = (char*)d_ws;
  u16* Xb  = (u16*)w; w += (size_t)NN * DIN * 2;
  u16* Yb  = (u16*)w; w += (size_t)NN * DH * 2;
  u16* H1b = (u16*)w; w += (size_t)NN * DH * 2;
  u16* H2b = (u16*)w; w += (size_t)NN * DH * 2;
  u16* W1T[3]; u16* W2T[3];
  W1T[0] = (u16*)w; w += (size_t)DIN * DH * 2;
  for (int l = 1; l < 3; ++l) { W1T[l] = (u16*)w; w += (size_t)DH * DH * 2; }
  for (int l = 0; l < 3; ++l) { W2T[l] = (u16*)w; w += (size_t)DH * DH * 2; }
  float* scsh = (float*)w; w += 3 * 512 * 4;
  float* PL = (float*)w; w += NG * 768 * 4;
  float* Q  = (float*)w; w += NG * 64 * 4;
  int* cnt  = (int*)w; w += (size_t)NN * 4;
  int* adj  = (int*)w; w += (size_t)NN * MAXDEG * 4;

  // ---- fused setup ----
  SetupArgs sa;
  sa.x = x; sa.Xb = Xb;
  sa.Wsrc[0] = W1[0]; sa.Wdst[0] = W1T[0];
  sa.Wsrc[1] = W1[1]; sa.Wdst[1] = W1T[1];
  sa.Wsrc[2] = W1[2]; sa.Wdst[2] = W1T[2];
  for (int l = 0; l < 3; ++l) { sa.Wsrc[3 + l] = W2[l]; sa.Wdst[3 + l] = W2T[l]; }
  for (int l = 0; l < 3; ++l) {
    sa.bn[l * 5 + 0] = b1[l]; sa.bn[l * 5 + 1] = ga[l]; sa.bn[l * 5 + 2] = be[l];
    sa.bn[l * 5 + 3] = mu[l]; sa.bn[l * 5 + 4] = va[l];
  }
  sa.scsh = scsh; sa.cnt = cnt; sa.PL = PL;
  k_setup<<<NB_X + NB_W + 3 + NB_Z, 256, 0, stream>>>(sa);

  // ---- adjacency build ----
  k_fill2<<<DIV_UP(NE, 256), 256, 0, stream>>>(src, dst, cnt, adj, NE);

  const int g1 = DIV_UP(NN, 128);   // 391 blocks
  const int g2 = DIV_UP(NN, 64);    // 782 blocks
  const u16* hin[3] = {Xb, H1b, H2b};
  u16* hout[3] = {H1b, H2b, H1b};   // layer 3 output unused (no store)

  for (int l = 0; l < 3; ++l) {
    if (l == 0)
      k_gemm1<512><<<g1, 512, 0, stream>>>(hin[l], W1T[l], Yb, NN);
    else
      k_gemm1<256><<<g1, 512, 0, stream>>>(hin[l], W1T[l], Yb, NN);
    if (l < 2)
      k_gin2<1><<<g2, 512, 0, stream>>>(Yb, cnt, adj, scsh + l * 512, W2T[l],
                                        b2[l], hout[l], batch, PL, 256 * l, NN);
    else
      k_gin2<0><<<g2, 512, 0, stream>>>(Yb, cnt, adj, scsh + l * 512, W2T[l],
                                        b2[l], hout[l], batch, PL, 256 * l, NN);
  }

  // ---- head ----
  k_head1<<<NG, 64, 0, stream>>>(PL, l1W, l1b, Q);
  k_head2<<<1, 64, 0, stream>>>(Q, l2W, l2b, out);
}

// Round 12
// 323.564 us; speedup vs baseline: 1.4916x; 1.4916x over previous
//
#include <hip/hip_runtime.h>
#include <hip/hip_bf16.h>

#define DIV_UP(a,b) (((a)+(b)-1)/(b))

static const int NN  = 50000;   // nodes
static const int NE  = 400000;  // edges
static const int DIN = 512;
static const int DH  = 256;
static const int NG  = 64;      // graphs
static const int MAXDEG = 64;   // Poisson(8) max over 50K nodes ~30; clamped

typedef unsigned short u16;
typedef unsigned int   u32;
typedef __attribute__((ext_vector_type(8))) short bf16x8;   // 8 bf16 (4 VGPRs)
typedef __attribute__((ext_vector_type(4))) float f32x4;

#define AS1(p) ((const __attribute__((address_space(1))) void*)(p))
#define AS3(p) ((__attribute__((address_space(3))) void*)(p))

__device__ inline u16 f2bf(float f) {
  u32 u = __float_as_uint(f);
  u += 0x7fffu + ((u >> 16) & 1u);   // round-to-nearest-even
  return (u16)(u >> 16);
}
__device__ inline float bf2f(u16 h) { return __uint_as_float(((u32)h) << 16); }
__device__ inline void unpack2(u32 u, float& lo, float& hi) {
  lo = __uint_as_float(u << 16);
  hi = __uint_as_float(u & 0xffff0000u);
}
__device__ inline u32 pack2(float lo, float hi) {
  return (u32)f2bf(lo) | ((u32)f2bf(hi) << 16);
}

// ================= fused setup: X cvt | 6 weight transposes | BN fold | zero
struct SetupArgs {
  const float* x; u16* Xb;
  const float* Wsrc[6]; u16* Wdst[6];      // [0]=W1L0 512x256, [1..2]=W1L1/2, [3..5]=W2L0..2
  const float* bn[15];                     // [l*5]: b1,gamma,beta,mean,var
  float* scsh;
  int* cnt; float* PL;
};
static const int NB_X = (NN * DIN / 8) / 256;                 // 12500
static const int NB_W = (131072 + 5 * 65536) / 256;           // 1792
static const int NB_Z = DIV_UP(NN + NG * 768, 256);           // 388

__global__ __launch_bounds__(256) void k_setup(SetupArgs a) {
  int b = blockIdx.x;
  if (b < NB_X) {
    int i = b * 256 + threadIdx.x;
    const float4* p = (const float4*)a.x + (size_t)i * 2;
    float4 f0 = p[0], f1 = p[1];
    uint4 o;
    o.x = pack2(f0.x, f0.y); o.y = pack2(f0.z, f0.w);
    o.z = pack2(f1.x, f1.y); o.w = pack2(f1.z, f1.w);
    ((uint4*)a.Xb)[i] = o;
  } else if (b < NB_X + NB_W) {
    int idx = (b - NB_X) * 256 + threadIdx.x;
    if (idx < 131072) {                       // W1[0]: K=512, N=256
      int n = idx >> 9, k = idx & 511;
      a.Wdst[0][idx] = f2bf(a.Wsrc[0][(size_t)k * 256 + n]);
    } else {
      int r = idx - 131072;
      int s = 1 + (r >> 16);
      int ri = r & 65535;
      int n = ri >> 8, k = ri & 255;
      a.Wdst[s][ri] = f2bf(a.Wsrc[s][(size_t)k * 256 + n]);
    }
  } else if (b < NB_X + NB_W + 3) {
    int l = b - NB_X - NB_W, ch = threadIdx.x;
    float sc = rsqrtf(a.bn[l * 5 + 4][ch] + 1e-5f) * a.bn[l * 5 + 1][ch];
    float sh = (a.bn[l * 5 + 0][ch] - a.bn[l * 5 + 3][ch]) * sc + a.bn[l * 5 + 2][ch];
    a.scsh[l * 512 + ch] = sc;
    a.scsh[l * 512 + 256 + ch] = sh;
  } else {
    int i = (b - NB_X - NB_W - 3) * 256 + threadIdx.x;
    if (i < NN) a.cnt[i] = 0;
    else if (i - NN < NG * 768) a.PL[i - NN] = 0.f;
  }
}

// ================= padded adjacency build ========
__global__ __launch_bounds__(256) void k_fill2(const int* __restrict__ src,
                                               const int* __restrict__ dst,
                                               int* __restrict__ cnt,
                                               int* __restrict__ adj, int nE) {
  int e = blockIdx.x * 256 + threadIdx.x;
  if (e >= nE) return;
  int d = dst[e];
  int pos = atomicAdd(&cnt[d], 1);
  if (pos < MAXDEG) adj[(size_t)d * MAXDEG + pos] = src[e];
}

// ============ gather core: a0..a7 = Y[gr] + sum_nbr Y[j] at channel c ======
__device__ inline void gather_row(const u16* __restrict__ Y, const int* __restrict__ cnt,
                                  const int* __restrict__ adj, int gr, int c,
                                  float& a0, float& a1, float& a2, float& a3,
                                  float& a4, float& a5, float& a6, float& a7) {
  uint4 v = *(const uint4*)(Y + (size_t)gr * DH + c);
  unpack2(v.x,a0,a1); unpack2(v.y,a2,a3); unpack2(v.z,a4,a5); unpack2(v.w,a6,a7);
  int deg = cnt[gr]; if (deg > MAXDEG) deg = MAXDEG;
  const int* row = adj + (size_t)gr * MAXDEG;
  int e = 0;
  for (; e + 8 <= deg; e += 8) {
    uint4 w[8];
#pragma unroll
    for (int u = 0; u < 8; ++u)
      w[u] = *(const uint4*)(Y + (size_t)row[e + u] * DH + c);
#pragma unroll
    for (int u = 0; u < 8; ++u) {
      float b0,b1,b2,b3,b4,b5,b6,b7;
      unpack2(w[u].x,b0,b1); unpack2(w[u].y,b2,b3);
      unpack2(w[u].z,b4,b5); unpack2(w[u].w,b6,b7);
      a0+=b0; a1+=b1; a2+=b2; a3+=b3; a4+=b4; a5+=b5; a6+=b6; a7+=b7;
    }
  }
  for (; e + 4 <= deg; e += 4) {
    uint4 w[4];
#pragma unroll
    for (int u = 0; u < 4; ++u)
      w[u] = *(const uint4*)(Y + (size_t)row[e + u] * DH + c);
#pragma unroll
    for (int u = 0; u < 4; ++u) {
      float b0,b1,b2,b3,b4,b5,b6,b7;
      unpack2(w[u].x,b0,b1); unpack2(w[u].y,b2,b3);
      unpack2(w[u].z,b4,b5); unpack2(w[u].w,b6,b7);
      a0+=b0; a1+=b1; a2+=b2; a3+=b3; a4+=b4; a5+=b5; a6+=b6; a7+=b7;
    }
  }
  for (; e < deg; ++e) {
    uint4 w = *(const uint4*)(Y + (size_t)row[e] * DH + c);
    float b0,b1,b2,b3,b4,b5,b6,b7;
    unpack2(w.x,b0,b1); unpack2(w.y,b2,b3); unpack2(w.z,b4,b5); unpack2(w.w,b6,b7);
    a0+=b0; a1+=b1; a2+=b2; a3+=b3; a4+=b4; a5+=b5; a6+=b6; a7+=b7;
  }
}

// ================= GEMM1: Y = A @ WT  (full-N 128x256 tile, BK=32, dbuf) ====
// Pre-swizzled global source for As/Bs (T21) -> 2-way LDS reads.
template <int K>
__global__ __launch_bounds__(512, 4) void k_gemm1(
    const u16* __restrict__ A, const u16* __restrict__ BT,
    u16* __restrict__ out, int M) {
  const int N = 256;
  __shared__ __align__(16) u16 sm[32768];   // staging 2x12288 head; Cs 32768 reuse
  u16* Cs = sm;
  const int bm = blockIdx.x * 128;
  const int tid = threadIdx.x;
  const int lane = tid & 63;
  const int wave = tid >> 6;        // 0..7
  const int wm = (wave >> 2) * 64;  // 0,64
  const int wn = (wave & 3) * 64;   // 0,64,128,192
  const int l15 = lane & 15;
  const int l4 = lane >> 4;
  const int sw = (lane >> 1) & 3;   // read-slot XOR
  const int srow = lane >> 2;
  const int sslot = (lane & 3) ^ ((lane >> 3) & 3);  // pre-swizzled source slot

  auto STAGE = [&](int buf, int k0) {
    u16* As = sm + buf * 12288;
    u16* Bs = As + 4096;
    {
      int row = wave * 16 + srow;
      int grA = bm + row; if (grA >= M) grA = M - 1;
      __builtin_amdgcn_global_load_lds(AS1(A + (size_t)grA * K + k0 + sslot * 8),
                                       AS3(As + wave * 512), 16, 0, 0);
    }
#pragma unroll
    for (int i = 0; i < 2; ++i) {
      int q = wave * 2 + i;
      int row = q * 16 + srow;
      __builtin_amdgcn_global_load_lds(AS1(BT + (size_t)row * K + k0 + sslot * 8),
                                       AS3(Bs + q * 512), 16, 0, 0);
    }
  };

  f32x4 acc[4][4] = {};
  const int nt = K >> 5;
  STAGE(0, 0);
  int cur = 0;
  for (int t = 0; t < nt; ++t) {
    __syncthreads();
    if (t + 1 < nt) STAGE(cur ^ 1, (t + 1) << 5);
    u16* As = sm + cur * 12288;
    u16* Bs = As + 4096;
    bf16x8 af[4], bf_[4];
#pragma unroll
    for (int f = 0; f < 4; ++f) {
      af[f]  = *(const bf16x8*)(As + (wm + f * 16 + l15) * 32 + ((l4 ^ sw) << 3));
      bf_[f] = *(const bf16x8*)(Bs + (wn + f * 16 + l15) * 32 + ((l4 ^ sw) << 3));
    }
#pragma unroll
    for (int i = 0; i < 4; ++i)
#pragma unroll
      for (int j = 0; j < 4; ++j)
        acc[i][j] = __builtin_amdgcn_mfma_f32_16x16x32_bf16(af[i], bf_[j], acc[i][j], 0, 0, 0);
    cur ^= 1;
  }

  __syncthreads();
#pragma unroll
  for (int j = 0; j < 4; ++j) {
    int n = wn + j * 16 + l15;
#pragma unroll
    for (int i = 0; i < 4; ++i) {
#pragma unroll
      for (int r = 0; r < 4; ++r) {
        int row = wm + i * 16 + l4 * 4 + r;
        Cs[row * 256 + n] = f2bf(acc[i][j][r]);
      }
    }
  }
  __syncthreads();
  const int ccol = (tid & 31) * 8;
#pragma unroll
  for (int p = 0; p < 8; ++p) {
    int row = p * 16 + (tid >> 5);
    int gm = bm + row;
    if (gm < M)
      *(uint4*)(out + (size_t)gm * N + ccol) = *(const uint4*)(Cs + row * 256 + ccol);
  }
}

// ====== fused GIN tail: gather+BN+relu -> LDS A-tile; h = relu(A@W2+b2);
//        fused per-graph pool; optional global h store.
// 32-row tile, 256 threads (4 waves: wave w owns cols w*64..w*64+63).
// B read directly from global (W2T L2-resident). LDS = At only (16.2 KB).
// __launch_bounds__(256,5): VGPR cap 102 (gather/MFMA reg lifetimes disjoint,
// peak ~80) -> 5 blocks/CU = 20 waves/CU. (R11 lesson: (512,8) cap 64 = spill.)
template <int STORE>
__global__ __launch_bounds__(256, 5) void k_gin2(
    const u16* __restrict__ Y, const int* __restrict__ cnt,
    const int* __restrict__ adj, const float* __restrict__ scsh,
    const u16* __restrict__ BT, const float* __restrict__ bias,
    u16* __restrict__ out, const int* __restrict__ batch,
    float* __restrict__ PL, int poolOff, int M) {
  __shared__ __align__(16) u16 At[32 * 256];     // 16 KB; swizzled; Cs reuse
  __shared__ int bsh[32];
  const int bm = blockIdx.x * 32;
  const int tid = threadIdx.x;
  const int lane = tid & 63;
  const int wave = tid >> 6;          // 0..3
  const int wn = wave * 64;           // 0,64,128,192
  const int l15 = lane & 15;
  const int l4 = lane >> 4;
  const int a7x = lane & 7;           // At read-row XOR

  if (tid < 32) bsh[tid] = (bm + tid < M) ? batch[bm + tid] : -1;

  // ---- gather 32 rows into swizzled At ----
  {
    const int c = (tid & 31) << 3;
    float4 sc0 = *(const float4*)(scsh + c);
    float4 sc1 = *(const float4*)(scsh + c + 4);
    float4 sh0 = *(const float4*)(scsh + 256 + c);
    float4 sh1 = *(const float4*)(scsh + 256 + c + 4);
    const int slot0 = c >> 3;           // logical 16B slot (0..31)
#pragma unroll 1
    for (int p = 0; p < 4; ++p) {
      int rl = p * 8 + (tid >> 5);      // local row 0..31
      int gr = bm + rl; if (gr >= M) gr = M - 1;
      float a0,a1,a2,a3,a4,a5,a6,a7v;
      gather_row(Y, cnt, adj, gr, c, a0,a1,a2,a3,a4,a5,a6,a7v);
      a0 = fmaxf(fmaf(a0, sc0.x, sh0.x), 0.f);
      a1 = fmaxf(fmaf(a1, sc0.y, sh0.y), 0.f);
      a2 = fmaxf(fmaf(a2, sc0.z, sh0.z), 0.f);
      a3 = fmaxf(fmaf(a3, sc0.w, sh0.w), 0.f);
      a4 = fmaxf(fmaf(a4, sc1.x, sh1.x), 0.f);
      a5 = fmaxf(fmaf(a5, sc1.y, sh1.y), 0.f);
      a6 = fmaxf(fmaf(a6, sc1.z, sh1.z), 0.f);
      a7v = fmaxf(fmaf(a7v, sc1.w, sh1.w), 0.f);
      uint4 o;
      o.x = pack2(a0,a1); o.y = pack2(a2,a3); o.z = pack2(a4,a5); o.w = pack2(a6,a7v);
      *(uint4*)(At + rl * 256 + ((slot0 ^ (rl & 7)) << 3)) = o;
    }
  }
  __syncthreads();                     // At ready; read-only through K-loop

  f32x4 acc[2][4] = {};
#pragma unroll 2
  for (int t = 0; t < 8; ++t) {
    bf16x8 af[2], bf_[4];
#pragma unroll
    for (int j = 0; j < 4; ++j) {
      int row = wn + j * 16 + l15;
      bf_[j] = *(const bf16x8*)(BT + (size_t)row * 256 + (t << 5) + l4 * 8);
    }
#pragma unroll
    for (int f = 0; f < 2; ++f) {
      int row = f * 16 + l15;
      af[f] = *(const bf16x8*)(At + row * 256 + ((((t << 2) + l4) ^ a7x) << 3));
    }
#pragma unroll
    for (int i = 0; i < 2; ++i)
#pragma unroll
      for (int j = 0; j < 4; ++j)
        acc[i][j] = __builtin_amdgcn_mfma_f32_16x16x32_bf16(af[i], bf_[j], acc[i][j], 0, 0, 0);
  }

  __syncthreads();            // At reads done; reuse as Cs
  u16* Cs = At;
#pragma unroll
  for (int j = 0; j < 4; ++j) {
    int n = wn + j * 16 + l15;
    float sh = bias[n];
#pragma unroll
    for (int i = 0; i < 2; ++i) {
#pragma unroll
      for (int r = 0; r < 4; ++r) {
        int row = i * 16 + l4 * 4 + r;
        Cs[row * 256 + n] = f2bf(fmaxf(acc[i][j][r] + sh, 0.f));
      }
    }
  }
  __syncthreads();

  if (STORE) {
    const int ccol = (tid & 31) * 8;
#pragma unroll
    for (int p = 0; p < 4; ++p) {
      int row = p * 8 + (tid >> 5);
      int gm = bm + row;
      if (gm < M)
        *(uint4*)(out + (size_t)gm * DH + ccol) = *(const uint4*)(Cs + row * 256 + ccol);
    }
  }

  {  // pool: 256 threads = 256 cols; run-length over 32 rows
    int col = tid;
    float accv = 0.f;
    int cg = bsh[0];
    for (int r = 0; r < 32; ++r) {
      int g = bsh[r];
      if (g != cg) {
        if (cg >= 0) unsafeAtomicAdd(&PL[cg * 768 + poolOff + col], accv);
        accv = 0.f;
        cg = g;
      }
      accv += bf2f(Cs[r * 256 + col]);
    }
    if (cg >= 0) unsafeAtomicAdd(&PL[cg * 768 + poolOff + col], accv);
  }
}

// ================= head =================
__global__ __launch_bounds__(64) void k_head1(const float* __restrict__ P,
                                              const float* __restrict__ W,
                                              const float* __restrict__ b,
                                              float* __restrict__ Q) {
  __shared__ float pr[768];
  int g = blockIdx.x, t = threadIdx.x;
  for (int i = t; i < 768; i += 64) pr[i] = P[g * 768 + i];
  __syncthreads();
  float acc = b[t];
  for (int k = 0; k < 768; ++k) acc = fmaf(pr[k], W[k * 64 + t], acc);
  Q[g * 64 + t] = fmaxf(acc, 0.f);
}

__global__ __launch_bounds__(64) void k_head2(const float* __restrict__ Q,
                                              const float* __restrict__ W,
                                              const float* __restrict__ b,
                                              float* __restrict__ out) {
  int g = threadIdx.x;
  if (g >= 64) return;
  float h0 = b[0], h1 = b[1];
  for (int k = 0; k < 64; ++k) {
    float q = Q[g * 64 + k];
    h0 = fmaf(q, W[k * 2 + 0], h0);
    h1 = fmaf(q, W[k * 2 + 1], h1);
  }
  out[g * 2 + 0] = h0;
  out[g * 2 + 1] = h1;
  float m = fmaxf(h0, h1);
  float lse = m + logf(expf(h0 - m) + expf(h1 - m));
  out[128 + g * 2 + 0] = h0 - lse;
  out[128 + g * 2 + 1] = h1 - lse;
}

extern "C" void kernel_launch(void* const* d_in, const int* in_sizes, int n_in,
                              void* d_out, int out_size, void* d_ws,
                              size_t ws_size, hipStream_t stream) {
  const float* x = (const float*)d_in[0];
  const int* ei = (const int*)d_in[1];
  const int* batch = (const int*)d_in[2];
  const float* W1[3]; const float* b1[3]; const float* ga[3]; const float* be[3];
  const float* mu[3]; const float* va[3]; const float* W2[3]; const float* b2[3];
  for (int l = 0; l < 3; ++l) {
    int base = 3 + 8 * l;
    W1[l] = (const float*)d_in[base + 0];
    b1[l] = (const float*)d_in[base + 1];
    ga[l] = (const float*)d_in[base + 2];
    be[l] = (const float*)d_in[base + 3];
    mu[l] = (const float*)d_in[base + 4];
    va[l] = (const float*)d_in[base + 5];
    W2[l] = (const float*)d_in[base + 6];
    b2[l] = (const float*)d_in[base + 7];
  }
  const float* l1W = (const float*)d_in[27];
  const float* l1b = (const float*)d_in[28];
  const float* l2W = (const float*)d_in[29];
  const float* l2b = (const float*)d_in[30];
  const int* src = ei;
  const int* dst = ei + NE;
  float* out = (float*)d_out;

  // ---- workspace layout ----
  char* w = (char*)d_ws;
  u16* Xb  = (u16*)w; w += (size_t)NN * DIN * 2;
  u16* Yb  = (u16*)w; w += (size_t)NN * DH * 2;
  u16* H1b = (u16*)w; w += (size_t)NN * DH * 2;
  u16* H2b = (u16*)w; w += (size_t)NN * DH * 2;
  u16* W1T[3]; u16* W2T[3];
  W1T[0] = (u16*)w; w += (size_t)DIN * DH * 2;
  for (int l = 1; l < 3; ++l) { W1T[l] = (u16*)w; w += (size_t)DH * DH * 2; }
  for (int l = 0; l < 3; ++l) { W2T[l] = (u16*)w; w += (size_t)DH * DH * 2; }
  float* scsh = (float*)w; w += 3 * 512 * 4;
  float* PL = (float*)w; w += NG * 768 * 4;
  float* Q  = (float*)w; w += NG * 64 * 4;
  int* cnt  = (int*)w; w += (size_t)NN * 4;
  int* adj  = (int*)w; w += (size_t)NN * MAXDEG * 4;

  // ---- fused setup ----
  SetupArgs sa;
  sa.x = x; sa.Xb = Xb;
  sa.Wsrc[0] = W1[0]; sa.Wdst[0] = W1T[0];
  sa.Wsrc[1] = W1[1]; sa.Wdst[1] = W1T[1];
  sa.Wsrc[2] = W1[2]; sa.Wdst[2] = W1T[2];
  for (int l = 0; l < 3; ++l) { sa.Wsrc[3 + l] = W2[l]; sa.Wdst[3 + l] = W2T[l]; }
  for (int l = 0; l < 3; ++l) {
    sa.bn[l * 5 + 0] = b1[l]; sa.bn[l * 5 + 1] = ga[l]; sa.bn[l * 5 + 2] = be[l];
    sa.bn[l * 5 + 3] = mu[l]; sa.bn[l * 5 + 4] = va[l];
  }
  sa.scsh = scsh; sa.cnt = cnt; sa.PL = PL;
  k_setup<<<NB_X + NB_W + 3 + NB_Z, 256, 0, stream>>>(sa);

  // ---- adjacency build ----
  k_fill2<<<DIV_UP(NE, 256), 256, 0, stream>>>(src, dst, cnt, adj, NE);

  const int g1 = DIV_UP(NN, 128);   // 391 blocks
  const int g2 = DIV_UP(NN, 32);    // 1563 blocks
  const u16* hin[3] = {Xb, H1b, H2b};
  u16* hout[3] = {H1b, H2b, H1b};   // layer 3 output unused (no store)

  for (int l = 0; l < 3; ++l) {
    if (l == 0)
      k_gemm1<512><<<g1, 512, 0, stream>>>(hin[l], W1T[l], Yb, NN);
    else
      k_gemm1<256><<<g1, 512, 0, stream>>>(hin[l], W1T[l], Yb, NN);
    if (l < 2)
      k_gin2<1><<<g2, 256, 0, stream>>>(Yb, cnt, adj, scsh + l * 512, W2T[l],
                                        b2[l], hout[l], batch, PL, 256 * l, NN);
    else
      k_gin2<0><<<g2, 256, 0, stream>>>(Yb, cnt, adj, scsh + l * 512, W2T[l],
                                        b2[l], hout[l], batch, PL, 256 * l, NN);
  }

  // ---- head ----
  k_head1<<<NG, 64, 0, stream>>>(PL, l1W, l1b, Q);
  k_head2<<<1, 64, 0, stream>>>(Q, l2W, l2b, out);
}

// Round 13
// 268.410 us; speedup vs baseline: 1.7981x; 1.2055x over previous
//
#include <hip/hip_runtime.h>
#include <hip/hip_bf16.h>

#define DIV_UP(a,b) (((a)+(b)-1)/(b))

static const int NN  = 50000;   // nodes
static const int NE  = 400000;  // edges
static const int DIN = 512;
static const int DH  = 256;
static const int NG  = 64;      // graphs
static const int MAXDEG = 64;   // Poisson(8) max over 50K nodes ~30; clamped

typedef unsigned short u16;
typedef unsigned int   u32;
typedef __attribute__((ext_vector_type(8))) short bf16x8;   // 8 bf16 (4 VGPRs)
typedef __attribute__((ext_vector_type(4))) float f32x4;

#define AS1(p) ((const __attribute__((address_space(1))) void*)(p))
#define AS3(p) ((__attribute__((address_space(3))) void*)(p))

__device__ inline u16 f2bf(float f) {
  u32 u = __float_as_uint(f);
  u += 0x7fffu + ((u >> 16) & 1u);   // round-to-nearest-even
  return (u16)(u >> 16);
}
__device__ inline float bf2f(u16 h) { return __uint_as_float(((u32)h) << 16); }
__device__ inline void unpack2(u32 u, float& lo, float& hi) {
  lo = __uint_as_float(u << 16);
  hi = __uint_as_float(u & 0xffff0000u);
}
__device__ inline u32 pack2(float lo, float hi) {
  return (u32)f2bf(lo) | ((u32)f2bf(hi) << 16);
}

// ======== setup: 6 weight transposes | BN fold | zero cnt/PL (no X cvt) ====
struct SetupArgs {
  const float* Wsrc[6]; u16* Wdst[6];      // [0]=W1L0 512x256, [1..2]=W1L1/2, [3..5]=W2L0..2
  const float* bn[15];                     // [l*5]: b1,gamma,beta,mean,var
  float* scsh;
  int* cnt; float* PL;
};
static const int NB_W = (131072 + 5 * 65536) / 256;           // 1792
static const int NB_Z = DIV_UP(NN + NG * 768, 256);           // 388

__global__ __launch_bounds__(256) void k_setup(SetupArgs a) {
  int b = blockIdx.x;
  if (b < NB_W) {
    int idx = b * 256 + threadIdx.x;
    if (idx < 131072) {                       // W1[0]: K=512, N=256
      int n = idx >> 9, k = idx & 511;
      a.Wdst[0][idx] = f2bf(a.Wsrc[0][(size_t)k * 256 + n]);
    } else {
      int r = idx - 131072;
      int s = 1 + (r >> 16);
      int ri = r & 65535;
      int n = ri >> 8, k = ri & 255;
      a.Wdst[s][ri] = f2bf(a.Wsrc[s][(size_t)k * 256 + n]);
    }
  } else if (b < NB_W + 3) {
    int l = b - NB_W, ch = threadIdx.x;
    float sc = rsqrtf(a.bn[l * 5 + 4][ch] + 1e-5f) * a.bn[l * 5 + 1][ch];
    float sh = (a.bn[l * 5 + 0][ch] - a.bn[l * 5 + 3][ch]) * sc + a.bn[l * 5 + 2][ch];
    a.scsh[l * 512 + ch] = sc;
    a.scsh[l * 512 + 256 + ch] = sh;
  } else {
    int i = (b - NB_W - 3) * 256 + threadIdx.x;
    if (i < NN) a.cnt[i] = 0;
    else if (i - NN < NG * 768) a.PL[i - NN] = 0.f;
  }
}

// ================= padded adjacency build ========
__global__ __launch_bounds__(256) void k_fill2(const int* __restrict__ src,
                                               const int* __restrict__ dst,
                                               int* __restrict__ cnt,
                                               int* __restrict__ adj, int nE) {
  int e = blockIdx.x * 256 + threadIdx.x;
  if (e >= nE) return;
  int d = dst[e];
  int pos = atomicAdd(&cnt[d], 1);
  if (pos < MAXDEG) adj[(size_t)d * MAXDEG + pos] = src[e];
}

// ============ gather core: a0..a7 = Y[gr] + sum_nbr Y[j] at channel c ======
__device__ inline void gather_row(const u16* __restrict__ Y, const int* __restrict__ cnt,
                                  const int* __restrict__ adj, int gr, int c,
                                  float& a0, float& a1, float& a2, float& a3,
                                  float& a4, float& a5, float& a6, float& a7) {
  uint4 v = *(const uint4*)(Y + (size_t)gr * DH + c);
  unpack2(v.x,a0,a1); unpack2(v.y,a2,a3); unpack2(v.z,a4,a5); unpack2(v.w,a6,a7);
  int deg = cnt[gr]; if (deg > MAXDEG) deg = MAXDEG;
  const int* row = adj + (size_t)gr * MAXDEG;
  int e = 0;
  for (; e + 8 <= deg; e += 8) {
    uint4 w[8];
#pragma unroll
    for (int u = 0; u < 8; ++u)
      w[u] = *(const uint4*)(Y + (size_t)row[e + u] * DH + c);
#pragma unroll
    for (int u = 0; u < 8; ++u) {
      float b0,b1,b2,b3,b4,b5,b6,b7;
      unpack2(w[u].x,b0,b1); unpack2(w[u].y,b2,b3);
      unpack2(w[u].z,b4,b5); unpack2(w[u].w,b6,b7);
      a0+=b0; a1+=b1; a2+=b2; a3+=b3; a4+=b4; a5+=b5; a6+=b6; a7+=b7;
    }
  }
  for (; e + 4 <= deg; e += 4) {
    uint4 w[4];
#pragma unroll
    for (int u = 0; u < 4; ++u)
      w[u] = *(const uint4*)(Y + (size_t)row[e + u] * DH + c);
#pragma unroll
    for (int u = 0; u < 4; ++u) {
      float b0,b1,b2,b3,b4,b5,b6,b7;
      unpack2(w[u].x,b0,b1); unpack2(w[u].y,b2,b3);
      unpack2(w[u].z,b4,b5); unpack2(w[u].w,b6,b7);
      a0+=b0; a1+=b1; a2+=b2; a3+=b3; a4+=b4; a5+=b5; a6+=b6; a7+=b7;
    }
  }
  for (; e < deg; ++e) {
    uint4 w = *(const uint4*)(Y + (size_t)row[e] * DH + c);
    float b0,b1,b2,b3,b4,b5,b6,b7;
    unpack2(w.x,b0,b1); unpack2(w.y,b2,b3); unpack2(w.z,b4,b5); unpack2(w.w,b6,b7);
    a0+=b0; a1+=b1; a2+=b2; a3+=b3; a4+=b4; a5+=b5; a6+=b6; a7+=b7;
  }
}

// ================= GEMM1: Y = A @ WT  (full-N 128x256 tile, BK=32, dbuf) ====
// F32A=1: A read directly from f32 source with in-register bf16 cvt
// (same swizzled LDS layout as the bf16 global_load_lds path).
template <int K, int F32A>
__global__ __launch_bounds__(512, 4) void k_gemm1(
    const u16* __restrict__ A, const float* __restrict__ A32,
    const u16* __restrict__ BT, u16* __restrict__ out, int M) {
  const int N = 256;
  __shared__ __align__(16) u16 sm[32768];   // staging 2x12288 head; Cs 32768 reuse
  u16* Cs = sm;
  const int bm = blockIdx.x * 128;
  const int tid = threadIdx.x;
  const int lane = tid & 63;
  const int wave = tid >> 6;        // 0..7
  const int wm = (wave >> 2) * 64;  // 0,64
  const int wn = (wave & 3) * 64;   // 0,64,128,192
  const int l15 = lane & 15;
  const int l4 = lane >> 4;
  const int sw = (lane >> 1) & 3;   // read-slot XOR
  const int srow = lane >> 2;
  const int sslot = (lane & 3) ^ ((lane >> 3) & 3);  // pre-swizzled source slot

  auto STAGE = [&](int buf, int k0) {
    u16* As = sm + buf * 12288;
    u16* Bs = As + 4096;
    {
      int row = wave * 16 + srow;
      int grA = bm + row; if (grA >= M) grA = M - 1;
      if (F32A) {
        const float* s = A32 + (size_t)grA * K + k0 + sslot * 8;
        float4 f0 = *(const float4*)s;
        float4 f1 = *(const float4*)(s + 4);
        uint4 o;
        o.x = pack2(f0.x, f0.y); o.y = pack2(f0.z, f0.w);
        o.z = pack2(f1.x, f1.y); o.w = pack2(f1.z, f1.w);
        *(uint4*)(As + row * 32 + (lane & 3) * 8) = o;
      } else {
        __builtin_amdgcn_global_load_lds(AS1(A + (size_t)grA * K + k0 + sslot * 8),
                                         AS3(As + wave * 512), 16, 0, 0);
      }
    }
#pragma unroll
    for (int i = 0; i < 2; ++i) {
      int q = wave * 2 + i;
      int row = q * 16 + srow;
      __builtin_amdgcn_global_load_lds(AS1(BT + (size_t)row * K + k0 + sslot * 8),
                                       AS3(Bs + q * 512), 16, 0, 0);
    }
  };

  f32x4 acc[4][4] = {};
  const int nt = K >> 5;
  STAGE(0, 0);
  int cur = 0;
  for (int t = 0; t < nt; ++t) {
    __syncthreads();
    if (t + 1 < nt) STAGE(cur ^ 1, (t + 1) << 5);
    u16* As = sm + cur * 12288;
    u16* Bs = As + 4096;
    bf16x8 af[4], bf_[4];
#pragma unroll
    for (int f = 0; f < 4; ++f) {
      af[f]  = *(const bf16x8*)(As + (wm + f * 16 + l15) * 32 + ((l4 ^ sw) << 3));
      bf_[f] = *(const bf16x8*)(Bs + (wn + f * 16 + l15) * 32 + ((l4 ^ sw) << 3));
    }
#pragma unroll
    for (int i = 0; i < 4; ++i)
#pragma unroll
      for (int j = 0; j < 4; ++j)
        acc[i][j] = __builtin_amdgcn_mfma_f32_16x16x32_bf16(af[i], bf_[j], acc[i][j], 0, 0, 0);
    cur ^= 1;
  }

  __syncthreads();
#pragma unroll
  for (int j = 0; j < 4; ++j) {
    int n = wn + j * 16 + l15;
#pragma unroll
    for (int i = 0; i < 4; ++i) {
#pragma unroll
      for (int r = 0; r < 4; ++r) {
        int row = wm + i * 16 + l4 * 4 + r;
        Cs[row * 256 + n] = f2bf(acc[i][j][r]);
      }
    }
  }
  __syncthreads();
  const int ccol = (tid & 31) * 8;
#pragma unroll
  for (int p = 0; p < 8; ++p) {
    int row = p * 16 + (tid >> 5);
    int gm = bm + row;
    if (gm < M)
      *(uint4*)(out + (size_t)gm * N + ccol) = *(const uint4*)(Cs + row * 256 + ccol);
  }
}

// ====== fused GIN tail (R10 config): gather+BN+relu -> swizzled LDS A-tile;
//        h = relu(A@W2+b2) with LDS-staged B dbuf; fused pool; opt store.
// 64-row tile, 512 threads, (512,4): VGPR ~60, LDS 66KB -> 2 blocks/CU.
template <int STORE>
__global__ __launch_bounds__(512, 4) void k_gin2(
    const u16* __restrict__ Y, const int* __restrict__ cnt,
    const int* __restrict__ adj, const float* __restrict__ scsh,
    const u16* __restrict__ BT, const float* __restrict__ bias,
    u16* __restrict__ out, const int* __restrict__ batch,
    float* __restrict__ PL, int poolOff, int M) {
  __shared__ __align__(16) u16 At[64 * 256];     // 32 KB; swizzled; Cs reuse
  __shared__ __align__(16) u16 Bs[2][8192];      // 2 x 16 KB
  __shared__ int bsh[64];
  const int bm = blockIdx.x * 64;
  const int tid = threadIdx.x;
  const int lane = tid & 63;
  const int wave = tid >> 6;          // 0..7
  const int wm = (wave >> 2) * 32;    // 0,32
  const int wn = (wave & 3) * 64;     // 0,64,128,192
  const int l15 = lane & 15;
  const int l4 = lane >> 4;
  const int sw = (lane >> 1) & 3;     // B read-slot XOR
  const int a7 = lane & 7;            // At read-row XOR
  const int sslot = (lane & 3) ^ ((lane >> 3) & 3);

  if (tid < 64) bsh[tid] = (bm + tid < M) ? batch[bm + tid] : -1;

  auto STAGE_B = [&](int buf, int k0) {
#pragma unroll
    for (int i = 0; i < 2; ++i) {
      int q = wave * 2 + i;
      int row = q * 16 + (lane >> 2);
      __builtin_amdgcn_global_load_lds(AS1(BT + (size_t)row * 256 + k0 + sslot * 8),
                                       AS3(&Bs[buf][q * 512]), 16, 0, 0);
    }
  };

  STAGE_B(0, 0);   // lands under the gather

  // ---- gather 64 rows into swizzled At ----
  {
    const int c = (tid & 31) << 3;
    float4 sc0 = *(const float4*)(scsh + c);
    float4 sc1 = *(const float4*)(scsh + c + 4);
    float4 sh0 = *(const float4*)(scsh + 256 + c);
    float4 sh1 = *(const float4*)(scsh + 256 + c + 4);
    const int slot0 = c >> 3;           // logical 16B slot (0..31)
#pragma unroll 1
    for (int p = 0; p < 4; ++p) {
      int rl = p * 16 + (tid >> 5);     // local row 0..63
      int gr = bm + rl; if (gr >= M) gr = M - 1;
      float a0,a1,a2,a3,a4,a5,a6,a7v;
      gather_row(Y, cnt, adj, gr, c, a0,a1,a2,a3,a4,a5,a6,a7v);
      a0 = fmaxf(fmaf(a0, sc0.x, sh0.x), 0.f);
      a1 = fmaxf(fmaf(a1, sc0.y, sh0.y), 0.f);
      a2 = fmaxf(fmaf(a2, sc0.z, sh0.z), 0.f);
      a3 = fmaxf(fmaf(a3, sc0.w, sh0.w), 0.f);
      a4 = fmaxf(fmaf(a4, sc1.x, sh1.x), 0.f);
      a5 = fmaxf(fmaf(a5, sc1.y, sh1.y), 0.f);
      a6 = fmaxf(fmaf(a6, sc1.z, sh1.z), 0.f);
      a7v = fmaxf(fmaf(a7v, sc1.w, sh1.w), 0.f);
      uint4 o;
      o.x = pack2(a0,a1); o.y = pack2(a2,a3); o.z = pack2(a4,a5); o.w = pack2(a6,a7v);
      *(uint4*)(At + rl * 256 + ((slot0 ^ (rl & 7)) << 3)) = o;
    }
  }

  f32x4 acc[2][4] = {};
  int cur = 0;
  for (int t = 0; t < 8; ++t) {
    __syncthreads();                       // At + Bs[cur] ready
    if (t + 1 < 8) STAGE_B(cur ^ 1, (t + 1) << 5);
    bf16x8 af[2], bf_[4];
#pragma unroll
    for (int f = 0; f < 2; ++f) {
      int row = wm + f * 16 + l15;
      af[f] = *(const bf16x8*)(At + row * 256 + ((((t << 2) + l4) ^ a7) << 3));
    }
#pragma unroll
    for (int j = 0; j < 4; ++j) {
      int row = wn + j * 16 + l15;
      bf_[j] = *(const bf16x8*)(&Bs[cur][row * 32 + ((l4 ^ sw) << 3)]);
    }
#pragma unroll
    for (int i = 0; i < 2; ++i)
#pragma unroll
      for (int j = 0; j < 4; ++j)
        acc[i][j] = __builtin_amdgcn_mfma_f32_16x16x32_bf16(af[i], bf_[j], acc[i][j], 0, 0, 0);
    cur ^= 1;
  }

  __syncthreads();            // At reads done; reuse as Cs
  u16* Cs = At;
#pragma unroll
  for (int j = 0; j < 4; ++j) {
    int n = wn + j * 16 + l15;
    float sh = bias[n];
#pragma unroll
    for (int i = 0; i < 2; ++i) {
#pragma unroll
      for (int r = 0; r < 4; ++r) {
        int row = wm + i * 16 + l4 * 4 + r;
        Cs[row * 256 + n] = f2bf(fmaxf(acc[i][j][r] + sh, 0.f));
      }
    }
  }
  __syncthreads();

  if (STORE) {
    const int ccol = (tid & 31) * 8;
#pragma unroll
    for (int p = 0; p < 4; ++p) {
      int row = p * 16 + (tid >> 5);
      int gm = bm + row;
      if (gm < M)
        *(uint4*)(out + (size_t)gm * DH + ccol) = *(const uint4*)(Cs + row * 256 + ccol);
    }
  }

  {  // pool: 2 halves x 32 rows, 256 cols
    int col = tid & 255;
    int half = tid >> 8;
    float accv = 0.f;
    int cg = bsh[half * 32];
    for (int r = 0; r < 32; ++r) {
      int row = half * 32 + r;
      int g = bsh[row];
      if (g != cg) {
        if (cg >= 0) unsafeAtomicAdd(&PL[cg * 768 + poolOff + col], accv);
        accv = 0.f;
        cg = g;
      }
      accv += bf2f(Cs[row * 256 + col]);
    }
    if (cg >= 0) unsafeAtomicAdd(&PL[cg * 768 + poolOff + col], accv);
  }
}

// ================= head =================
__global__ __launch_bounds__(64) void k_head1(const float* __restrict__ P,
                                              const float* __restrict__ W,
                                              const float* __restrict__ b,
                                              float* __restrict__ Q) {
  __shared__ float pr[768];
  int g = blockIdx.x, t = threadIdx.x;
  for (int i = t; i < 768; i += 64) pr[i] = P[g * 768 + i];
  __syncthreads();
  float acc = b[t];
  for (int k = 0; k < 768; ++k) acc = fmaf(pr[k], W[k * 64 + t], acc);
  Q[g * 64 + t] = fmaxf(acc, 0.f);
}

__global__ __launch_bounds__(64) void k_head2(const float* __restrict__ Q,
                                              const float* __restrict__ W,
                                              const float* __restrict__ b,
                                              float* __restrict__ out) {
  int g = threadIdx.x;
  if (g >= 64) return;
  float h0 = b[0], h1 = b[1];
  for (int k = 0; k < 64; ++k) {
    float q = Q[g * 64 + k];
    h0 = fmaf(q, W[k * 2 + 0], h0);
    h1 = fmaf(q, W[k * 2 + 1], h1);
  }
  out[g * 2 + 0] = h0;
  out[g * 2 + 1] = h1;
  float m = fmaxf(h0, h1);
  float lse = m + logf(expf(h0 - m) + expf(h1 - m));
  out[128 + g * 2 + 0] = h0 - lse;
  out[128 + g * 2 + 1] = h1 - lse;
}

extern "C" void kernel_launch(void* const* d_in, const int* in_sizes, int n_in,
                              void* d_out, int out_size, void* d_ws,
                              size_t ws_size, hipStream_t stream) {
  const float* x = (const float*)d_in[0];
  const int* ei = (const int*)d_in[1];
  const int* batch = (const int*)d_in[2];
  const float* W1[3]; const float* b1[3]; const float* ga[3]; const float* be[3];
  const float* mu[3]; const float* va[3]; const float* W2[3]; const float* b2[3];
  for (int l = 0; l < 3; ++l) {
    int base = 3 + 8 * l;
    W1[l] = (const float*)d_in[base + 0];
    b1[l] = (const float*)d_in[base + 1];
    ga[l] = (const float*)d_in[base + 2];
    be[l] = (const float*)d_in[base + 3];
    mu[l] = (const float*)d_in[base + 4];
    va[l] = (const float*)d_in[base + 5];
    W2[l] = (const float*)d_in[base + 6];
    b2[l] = (const float*)d_in[base + 7];
  }
  const float* l1W = (const float*)d_in[27];
  const float* l1b = (const float*)d_in[28];
  const float* l2W = (const float*)d_in[29];
  const float* l2b = (const float*)d_in[30];
  const int* src = ei;
  const int* dst = ei + NE;
  float* out = (float*)d_out;

  // ---- workspace layout (Xb removed) ----
  char* w = (char*)d_ws;
  u16* Yb  = (u16*)w; w += (size_t)NN * DH * 2;
  u16* H1b = (u16*)w; w += (size_t)NN * DH * 2;
  u16* H2b = (u16*)w; w += (size_t)NN * DH * 2;
  u16* W1T[3]; u16* W2T[3];
  W1T[0] = (u16*)w; w += (size_t)DIN * DH * 2;
  for (int l = 1; l < 3; ++l) { W1T[l] = (u16*)w; w += (size_t)DH * DH * 2; }
  for (int l = 0; l < 3; ++l) { W2T[l] = (u16*)w; w += (size_t)DH * DH * 2; }
  float* scsh = (float*)w; w += 3 * 512 * 4;
  float* PL = (float*)w; w += NG * 768 * 4;
  float* Q  = (float*)w; w += NG * 64 * 4;
  int* cnt  = (int*)w; w += (size_t)NN * 4;
  int* adj  = (int*)w; w += (size_t)NN * MAXDEG * 4;

  // ---- setup (weights + BN fold + zeroing; no X conversion) ----
  SetupArgs sa;
  sa.Wsrc[0] = W1[0]; sa.Wdst[0] = W1T[0];
  sa.Wsrc[1] = W1[1]; sa.Wdst[1] = W1T[1];
  sa.Wsrc[2] = W1[2]; sa.Wdst[2] = W1T[2];
  for (int l = 0; l < 3; ++l) { sa.Wsrc[3 + l] = W2[l]; sa.Wdst[3 + l] = W2T[l]; }
  for (int l = 0; l < 3; ++l) {
    sa.bn[l * 5 + 0] = b1[l]; sa.bn[l * 5 + 1] = ga[l]; sa.bn[l * 5 + 2] = be[l];
    sa.bn[l * 5 + 3] = mu[l]; sa.bn[l * 5 + 4] = va[l];
  }
  sa.scsh = scsh; sa.cnt = cnt; sa.PL = PL;
  k_setup<<<NB_W + 3 + NB_Z, 256, 0, stream>>>(sa);

  // ---- adjacency build ----
  k_fill2<<<DIV_UP(NE, 256), 256, 0, stream>>>(src, dst, cnt, adj, NE);

  const int g1 = DIV_UP(NN, 128);   // 391 blocks
  const int g2 = DIV_UP(NN, 64);    // 782 blocks
  const u16* hin[3] = {nullptr, H1b, H2b};
  u16* hout[3] = {H1b, H2b, H1b};   // layer 3 output unused (no store)

  for (int l = 0; l < 3; ++l) {
    if (l == 0)
      k_gemm1<512, 1><<<g1, 512, 0, stream>>>(nullptr, x, W1T[0], Yb, NN);
    else
      k_gemm1<256, 0><<<g1, 512, 0, stream>>>(hin[l], nullptr, W1T[l], Yb, NN);
    if (l < 2)
      k_gin2<1><<<g2, 512, 0, stream>>>(Yb, cnt, adj, scsh + l * 512, W2T[l],
                                        b2[l], hout[l], batch, PL, 256 * l, NN);
    else
      k_gin2<0><<<g2, 512, 0, stream>>>(Yb, cnt, adj, scsh + l * 512, W2T[l],
                                        b2[l], hout[l], batch, PL, 256 * l, NN);
  }

  // ---- head ----
  k_head1<<<NG, 64, 0, stream>>>(PL, l1W, l1b, Q);
  k_head2<<<1, 64, 0, stream>>>(Q, l2W, l2b, out);
}